// Round 1
// baseline (1337.176 us; speedup 1.0000x reference)
//
#include <hip/hip_runtime.h>
#include <hip/hip_bf16.h>
#include <math.h>

// Problem constants
#define BATCH 2
#define LSEQ 1024
#define DMODEL 1024
#define DINNER 2048
#define DSTATE 16
#define DTRANK 64
#define KCONV 4
#define NROWS (BATCH * LSEQ)          // 2048 token rows
#define XPROJ_N (DTRANK + 2 * DSTATE) // 96

// ---------------------------------------------------------------------------
// RMSNorm: one block per token row (1024 elems), 256 threads x 4 elems
// ---------------------------------------------------------------------------
__global__ __launch_bounds__(256) void rmsnorm_kernel(
    const float* __restrict__ x, const float* __restrict__ w,
    float* __restrict__ h)
{
    int row = blockIdx.x;
    int tid = threadIdx.x;
    const float* xr = x + (long)row * DMODEL;
    float4 v = *(const float4*)(xr + tid * 4);
    float ss = v.x * v.x + v.y * v.y + v.z * v.z + v.w * v.w;
    // wave64 butterfly
    #pragma unroll
    for (int m = 32; m >= 1; m >>= 1) ss += __shfl_xor(ss, m);
    __shared__ float ws[4];
    if ((tid & 63) == 0) ws[tid >> 6] = ss;
    __syncthreads();
    float total = ws[0] + ws[1] + ws[2] + ws[3];
    float scale = rsqrtf(total * (1.0f / DMODEL) + 1e-5f);
    float4 wv = *(const float4*)(w + tid * 4);
    float4 o;
    o.x = v.x * scale * wv.x;
    o.y = v.y * scale * wv.y;
    o.z = v.z * scale * wv.z;
    o.w = v.w * scale * wv.w;
    *(float4*)(h + (long)row * DMODEL + tid * 4) = o;
}

// ---------------------------------------------------------------------------
// Generic fp32 tiled GEMM: C[M,N] = A[M,K] @ B[K,N]  (row-major, strides lda/ldb/ldc)
// mode 0: C = acc
// mode 1: C = softplus(acc + bias[n])
// mode 2: C = acc + resid[m*ldc + n]
// Tile 64x64, BK=16, 256 threads, 4x4 per thread.
// ---------------------------------------------------------------------------
#define BM 64
#define BN 64
#define BKT 16

__device__ __forceinline__ float softplus_f(float v) {
    return (v > 20.0f) ? v : log1pf(__expf(v));
}

__global__ __launch_bounds__(256) void sgemm_kernel(
    const float* __restrict__ A, int lda,
    const float* __restrict__ B, int ldb,
    float* __restrict__ C, int ldc,
    int M, int N, int Kd,
    const float* __restrict__ bias,
    const float* __restrict__ resid,
    int mode)
{
    __shared__ __attribute__((aligned(16))) float As[BKT][BM + 4];
    __shared__ __attribute__((aligned(16))) float Bs[BKT][BN];
    int tid = threadIdx.x;
    int tx = tid & 15, ty = tid >> 4;
    int row0 = blockIdx.y * BM, col0 = blockIdx.x * BN;
    float acc[4][4] = {};

    for (int k0 = 0; k0 < Kd; k0 += BKT) {
        // Load A tile (64x16): thread loads 4 elems; consecutive tid -> consecutive k
        #pragma unroll
        for (int i = 0; i < 4; ++i) {
            int idx = tid + i * 256;
            int m = idx >> 4;
            int kk = idx & 15;
            int gm = row0 + m, gk = k0 + kk;
            float v = (gm < M && gk < Kd) ? A[(long)gm * lda + gk] : 0.0f;
            As[kk][m] = v;
        }
        // Load B tile (16x64): consecutive tid -> consecutive n (coalesced)
        #pragma unroll
        for (int i = 0; i < 4; ++i) {
            int idx = tid + i * 256;
            int kk = idx >> 6;
            int n = idx & 63;
            int gk = k0 + kk, gn = col0 + n;
            float v = (gk < Kd && gn < N) ? B[(long)gk * ldb + gn] : 0.0f;
            Bs[kk][n] = v;
        }
        __syncthreads();
        #pragma unroll
        for (int kk = 0; kk < BKT; ++kk) {
            float4 av = *(const float4*)&As[kk][ty * 4];
            float4 bv = *(const float4*)&Bs[kk][tx * 4];
            float a[4] = {av.x, av.y, av.z, av.w};
            float b[4] = {bv.x, bv.y, bv.z, bv.w};
            #pragma unroll
            for (int i = 0; i < 4; ++i) {
                #pragma unroll
                for (int j = 0; j < 4; ++j) acc[i][j] += a[i] * b[j];
            }
        }
        __syncthreads();
    }

    #pragma unroll
    for (int i = 0; i < 4; ++i) {
        int gm = row0 + ty * 4 + i;
        if (gm >= M) continue;
        #pragma unroll
        for (int j = 0; j < 4; ++j) {
            int gn = col0 + tx * 4 + j;
            if (gn >= N) continue;
            float v = acc[i][j];
            if (mode == 1) v = softplus_f(v + bias[gn]);
            else if (mode == 2) v = v + resid[(long)gm * ldc + gn];
            C[(long)gm * ldc + gn] = v;
        }
    }
}

// ---------------------------------------------------------------------------
// Causal depthwise conv (K=4) + bias + SiLU.
// x lives in xz[:, 0:2048] (row stride 4096). Output xc [NROWS, 2048].
// ---------------------------------------------------------------------------
__global__ __launch_bounds__(256) void conv_silu_kernel(
    const float* __restrict__ xz, const float* __restrict__ conv_w,
    const float* __restrict__ conv_b, float* __restrict__ xc)
{
    int idx = blockIdx.x * 256 + threadIdx.x;   // over NROWS*DINNER
    int c = idx & (DINNER - 1);
    int row = idx >> 11;
    int l = row & (LSEQ - 1);
    float w0 = conv_w[c * 4 + 0];
    float w1 = conv_w[c * 4 + 1];
    float w2 = conv_w[c * 4 + 2];
    float w3 = conv_w[c * 4 + 3];
    const float* xr = xz + (long)row * (2 * DINNER) + c;
    float acc = conv_b[c] + xr[0] * w3;
    if (l >= 1) acc += xr[-1 * 2 * DINNER] * w2;
    if (l >= 2) acc += xr[-2 * 2 * DINNER] * w1;
    if (l >= 3) acc += xr[-3 * 2 * DINNER] * w0;
    float s = acc / (1.0f + __expf(-acc));   // silu
    xc[(long)row * DINNER + c] = s;
}

// ---------------------------------------------------------------------------
// Selective scan. Block = 256 threads = 16 channels x 16 states, one batch b.
// Grid = BATCH * DINNER/16 = 256 blocks. LDS-staged chunks of 64 timesteps.
// ---------------------------------------------------------------------------
#define SCAN_T 64
__global__ __launch_bounds__(256) void scan_kernel(
    const float* __restrict__ delta,  // [NROWS, DINNER]
    const float* __restrict__ xc,     // [NROWS, DINNER]
    const float* __restrict__ xdbl,   // [NROWS, 96]; B at col 64, C at col 80
    const float* __restrict__ A,      // [DINNER, DSTATE]
    float* __restrict__ y)            // [NROWS, DINNER]
{
    __shared__ float sB[SCAN_T][16];
    __shared__ float sC[SCAN_T][16];
    __shared__ float sD[SCAN_T][16];
    __shared__ float sX[SCAN_T][16];
    int b = blockIdx.x >> 7;                // 128 blocks per batch
    int d_base = (blockIdx.x & 127) << 4;
    int tid = threadIdx.x;
    int ch = tid >> 4, n = tid & 15;
    int d = d_base + ch;
    float A_dn = A[d * DSTATE + n];
    float state = 0.0f;

    for (int l0 = 0; l0 < LSEQ; l0 += SCAN_T) {
        __syncthreads();   // protect previous chunk's LDS reads
        #pragma unroll
        for (int i = 0; i < 4; ++i) {
            int idx = tid + i * 256;
            int lt = idx >> 4;
            int j = idx & 15;
            long rowoff = (long)(b * LSEQ + l0 + lt);
            sB[lt][j] = xdbl[rowoff * XPROJ_N + DTRANK + j];
            sC[lt][j] = xdbl[rowoff * XPROJ_N + DTRANK + DSTATE + j];
            sD[lt][j] = delta[rowoff * DINNER + d_base + j];
            sX[lt][j] = xc[rowoff * DINNER + d_base + j];
        }
        __syncthreads();
        for (int lt = 0; lt < SCAN_T; ++lt) {
            float dv = sD[lt][ch];
            float xv = sX[lt][ch];
            float Bv = sB[lt][n];
            float Cv = sC[lt][n];
            float dA = __expf(dv * A_dn);
            state = dA * state + dv * xv * Bv;
            float prod = state * Cv;
            prod += __shfl_xor(prod, 1);
            prod += __shfl_xor(prod, 2);
            prod += __shfl_xor(prod, 4);
            prod += __shfl_xor(prod, 8);
            if (n == 0) y[(long)(b * LSEQ + l0 + lt) * DINNER + d] = prod;
        }
    }
}

// ---------------------------------------------------------------------------
// y = (ys + xc*D[c]) * silu(res);  res = xz[:, 2048 + c]
// ---------------------------------------------------------------------------
__global__ __launch_bounds__(256) void ymod_kernel(
    float* __restrict__ y, const float* __restrict__ xc,
    const float* __restrict__ xz, const float* __restrict__ Dp)
{
    int idx = blockIdx.x * 256 + threadIdx.x;
    int c = idx & (DINNER - 1);
    int row = idx >> 11;
    float res = xz[(long)row * (2 * DINNER) + DINNER + c];
    float sres = res / (1.0f + __expf(-res));
    y[idx] = (y[idx] + xc[idx] * Dp[c]) * sres;
}

// ---------------------------------------------------------------------------
extern "C" void kernel_launch(void* const* d_in, const int* in_sizes, int n_in,
                              void* d_out, int out_size, void* d_ws, size_t ws_size,
                              hipStream_t stream)
{
    const float* x0     = (const float*)d_in[0];  // [2,1024,1024]
    const float* norm_w = (const float*)d_in[1];  // [1024]
    const float* W_in   = (const float*)d_in[2];  // [1024,4096]
    const float* conv_w = (const float*)d_in[3];  // [2048,4]
    const float* conv_b = (const float*)d_in[4];  // [2048]
    const float* W_x    = (const float*)d_in[5];  // [2048,96]
    const float* W_dt   = (const float*)d_in[6];  // [64,2048]
    const float* b_dt   = (const float*)d_in[7];  // [2048]
    const float* A      = (const float*)d_in[8];  // [2048,16]
    const float* Dp     = (const float*)d_in[9];  // [2048]
    const float* W_out  = (const float*)d_in[10]; // [2048,1024]
    float* out = (float*)d_out;                   // [2,1024,1024]

    // Workspace layout (floats)
    float* ws = (float*)d_ws;
    float* h     = ws;                                   // 2048*1024
    float* xz    = h     + (long)NROWS * DMODEL;         // 2048*4096
    float* xc    = xz    + (long)NROWS * 2 * DINNER;     // 2048*2048
    float* xdbl  = xc    + (long)NROWS * DINNER;         // 2048*96
    float* delta = xdbl  + (long)NROWS * XPROJ_N;        // 2048*2048
    float* ybuf  = delta + (long)NROWS * DINNER;         // 2048*2048

    // 1. RMSNorm
    rmsnorm_kernel<<<NROWS, 256, 0, stream>>>(x0, norm_w, h);

    // 2. xz = h @ W_in   [2048,1024]x[1024,4096]
    {
        dim3 grid(2 * DINNER / BN, NROWS / BM);
        sgemm_kernel<<<grid, 256, 0, stream>>>(h, DMODEL, W_in, 2 * DINNER,
                                               xz, 2 * DINNER,
                                               NROWS, 2 * DINNER, DMODEL,
                                               nullptr, nullptr, 0);
    }

    // 3. causal conv + silu -> xc
    conv_silu_kernel<<<(NROWS * DINNER) / 256, 256, 0, stream>>>(xz, conv_w, conv_b, xc);

    // 4. xdbl = xc @ W_x  [2048,2048]x[2048,96]
    {
        dim3 grid((XPROJ_N + BN - 1) / BN, NROWS / BM);
        sgemm_kernel<<<grid, 256, 0, stream>>>(xc, DINNER, W_x, XPROJ_N,
                                               xdbl, XPROJ_N,
                                               NROWS, XPROJ_N, DINNER,
                                               nullptr, nullptr, 0);
    }

    // 5. delta = softplus(xdbl[:, :64] @ W_dt + b_dt)  [2048,64]x[64,2048]
    {
        dim3 grid(DINNER / BN, NROWS / BM);
        sgemm_kernel<<<grid, 256, 0, stream>>>(xdbl, XPROJ_N, W_dt, DINNER,
                                               delta, DINNER,
                                               NROWS, DINNER, DTRANK,
                                               b_dt, nullptr, 1);
    }

    // 6. selective scan -> ybuf
    scan_kernel<<<BATCH * (DINNER / 16), 256, 0, stream>>>(delta, xc, xdbl, A, ybuf);

    // 7. y = (ys + xc*D) * silu(res)
    ymod_kernel<<<(NROWS * DINNER) / 256, 256, 0, stream>>>(ybuf, xc, xz, Dp);

    // 8. out = x0 + y @ W_out  [2048,2048]x[2048,1024]
    {
        dim3 grid(DMODEL / BN, NROWS / BM);
        sgemm_kernel<<<grid, 256, 0, stream>>>(ybuf, DINNER, W_out, DMODEL,
                                               out, DMODEL,
                                               NROWS, DMODEL, DINNER,
                                               nullptr, x0, 2);
    }
}

// Round 2
// 494.224 us; speedup vs baseline: 2.7056x; 2.7056x over previous
//
#include <hip/hip_runtime.h>
#include <hip/hip_bf16.h>
#include <math.h>

// Problem constants
#define BATCH 2
#define LSEQ 1024
#define DMODEL 1024
#define DINNER 2048
#define DSTATE 16
#define DTRANK 64
#define NROWS (BATCH * LSEQ)   // 2048 token rows
#define XROW 128               // padded xdbl row stride (96 -> 128)

typedef __bf16 bf16;
typedef __attribute__((ext_vector_type(8))) __bf16 bf16x8;
typedef __attribute__((ext_vector_type(4))) float floatx4;

// ---------------------------------------------------------------------------
// bf16 MFMA GEMM, m97-style: 128x128 tile, BK=32, global_load_lds width-16.
// A:  [M][lda] bf16 row-major (activations)
// Bt: [N][ldb] bf16 row-major = B transposed (weights, pre-transposed)
// C:  [M][ldc] fp32 (or bf16 when BF16OUT)
// MODE 0: C = acc            MODE 1: C = softplus(acc + bias[n])
// MODE 2: C = acc + resid    MODE 3: atomicAdd(C, acc)  (split-K over blockIdx.z)
// ---------------------------------------------------------------------------
#define TM 128
#define TN 128
#define TK 32

__device__ __forceinline__ void glds16(const bf16* g, bf16* l) {
    __builtin_amdgcn_global_load_lds(
        (const __attribute__((address_space(1))) void*)g,
        (__attribute__((address_space(3))) void*)l, 16, 0, 0);
}

template<int MODE, bool BF16OUT>
__global__ __launch_bounds__(256) void gemm_bf16_kernel(
    const bf16* __restrict__ A, int lda,
    const bf16* __restrict__ Bt, int ldb,
    void* __restrict__ Cv, int ldc,
    int Ksplit,
    const float* __restrict__ bias,
    const float* __restrict__ resid, int ldr)
{
    __shared__ __attribute__((aligned(16))) bf16 As[TM * TK];
    __shared__ __attribute__((aligned(16))) bf16 Bs[TN * TK];

    const int tid  = threadIdx.x;
    const int lane = tid & 63;
    const int wave = tid >> 6;       // 4 waves: 2x2 grid of 64x64
    const int l15  = lane & 15;
    const int quad = lane >> 4;
    const int wm   = (wave >> 1) * 64;
    const int wn   = (wave & 1) * 64;

    const int row0 = blockIdx.y * TM;
    const int col0 = blockIdx.x * TN;
    const long kbase = (long)blockIdx.z * Ksplit;

    // staging chunk for this thread (issue 0: chunks 0..255, issue 1: +256)
    // chunk c covers LDS bytes c*16 = tile row c>>2, k-part (c&3)*8
    const int c0   = wave * 64 + lane;
    const int crow = c0 >> 2;
    const int ckq  = (c0 & 3) * 8;

    const bf16* gA0 = A  + (size_t)(row0 + crow) * lda + kbase + ckq;
    const bf16* gA1 = gA0 + (size_t)64 * lda;
    const bf16* gB0 = Bt + (size_t)(col0 + crow) * ldb + kbase + ckq;
    const bf16* gB1 = gB0 + (size_t)64 * ldb;

    bf16* lA0 = As + wave * 64 * 8;          // wave-uniform LDS bases
    bf16* lA1 = As + (256 + wave * 64) * 8;
    bf16* lB0 = Bs + wave * 64 * 8;
    bf16* lB1 = Bs + (256 + wave * 64) * 8;

    floatx4 acc[4][4];
    #pragma unroll
    for (int i = 0; i < 4; ++i)
        #pragma unroll
        for (int j = 0; j < 4; ++j)
            acc[i][j] = (floatx4){0.f, 0.f, 0.f, 0.f};

    const int kiters = Ksplit / TK;
    for (int kk = 0; kk < kiters; ++kk) {
        __syncthreads();                      // protect previous iter's LDS reads
        glds16(gA0, lA0);
        glds16(gA1, lA1);
        glds16(gB0, lB0);
        glds16(gB1, lB1);
        gA0 += TK; gA1 += TK; gB0 += TK; gB1 += TK;
        __syncthreads();                      // barrier drains vmcnt -> data visible

        bf16x8 af[4], bfr[4];
        #pragma unroll
        for (int i = 0; i < 4; ++i)
            af[i] = *(const bf16x8*)&As[(wm + i * 16 + l15) * TK + quad * 8];
        #pragma unroll
        for (int j = 0; j < 4; ++j)
            bfr[j] = *(const bf16x8*)&Bs[(wn + j * 16 + l15) * TK + quad * 8];
        #pragma unroll
        for (int i = 0; i < 4; ++i)
            #pragma unroll
            for (int j = 0; j < 4; ++j)
                acc[i][j] = __builtin_amdgcn_mfma_f32_16x16x32_bf16(
                                af[i], bfr[j], acc[i][j], 0, 0, 0);
    }

    // epilogue: D frag mapping col=lane&15, row=quad*4+reg
    #pragma unroll
    for (int i = 0; i < 4; ++i) {
        #pragma unroll
        for (int j = 0; j < 4; ++j) {
            const int gn = col0 + wn + j * 16 + l15;
            #pragma unroll
            for (int r = 0; r < 4; ++r) {
                const int gm = row0 + wm + i * 16 + quad * 4 + r;
                float v = acc[i][j][r];
                if (MODE == 1) {
                    v += bias[gn];
                    v = (v > 20.0f) ? v : log1pf(__expf(v));
                }
                if (MODE == 2) v += resid[(size_t)gm * ldr + gn];
                if (MODE == 3) {
                    atomicAdd(&((float*)Cv)[(size_t)gm * ldc + gn], v);
                } else if (BF16OUT) {
                    ((bf16*)Cv)[(size_t)gm * ldc + gn] = (bf16)v;
                } else {
                    ((float*)Cv)[(size_t)gm * ldc + gn] = v;
                }
            }
        }
    }
}

// ---------------------------------------------------------------------------
// Transpose-convert: W [K][N] fp32 -> Wt [Npad][K] bf16, zero-fill n>=N.
// ---------------------------------------------------------------------------
__global__ __launch_bounds__(256) void transpose_bf16_kernel(
    const float* __restrict__ W, bf16* __restrict__ Wt,
    int K, int N, int Npad)
{
    __shared__ float tile[32][33];
    const int n0 = blockIdx.x * 32;
    const int k0 = blockIdx.y * 32;
    const int tx = threadIdx.x & 31;
    const int ty = threadIdx.x >> 5;   // 0..7
    #pragma unroll
    for (int i = 0; i < 32; i += 8) {
        int k = k0 + ty + i, n = n0 + tx;
        tile[ty + i][tx] = (k < K && n < N) ? W[(size_t)k * N + n] : 0.0f;
    }
    __syncthreads();
    #pragma unroll
    for (int i = 0; i < 32; i += 8) {
        int n = n0 + ty + i, k = k0 + tx;
        if (n < Npad && k < K)
            Wt[(size_t)n * K + k] = (bf16)tile[tx][ty + i];
    }
}

// ---------------------------------------------------------------------------
// RMSNorm -> bf16 h. One block per token row.
// ---------------------------------------------------------------------------
__global__ __launch_bounds__(256) void rmsnorm_kernel(
    const float* __restrict__ x, const float* __restrict__ w,
    bf16* __restrict__ h)
{
    int row = blockIdx.x;
    int tid = threadIdx.x;
    const float* xr = x + (size_t)row * DMODEL;
    float4 v = *(const float4*)(xr + tid * 4);
    float ss = v.x * v.x + v.y * v.y + v.z * v.z + v.w * v.w;
    #pragma unroll
    for (int m = 32; m >= 1; m >>= 1) ss += __shfl_xor(ss, m);
    __shared__ float ws[4];
    if ((tid & 63) == 0) ws[tid >> 6] = ss;
    __syncthreads();
    float total = ws[0] + ws[1] + ws[2] + ws[3];
    float scale = rsqrtf(total * (1.0f / DMODEL) + 1e-5f);
    float4 wv = *(const float4*)(w + tid * 4);
    union { bf16 b[4]; uint2 u; } pk;
    pk.b[0] = (bf16)(v.x * scale * wv.x);
    pk.b[1] = (bf16)(v.y * scale * wv.y);
    pk.b[2] = (bf16)(v.z * scale * wv.z);
    pk.b[3] = (bf16)(v.w * scale * wv.w);
    *(uint2*)(h + (size_t)row * DMODEL + tid * 4) = pk.u;
}

// ---------------------------------------------------------------------------
// Causal depthwise conv (K=4) + bias + SiLU. x half of xz (bf16, stride 4096).
// ---------------------------------------------------------------------------
__global__ __launch_bounds__(256) void conv_silu_kernel(
    const bf16* __restrict__ xz, const float* __restrict__ conv_w,
    const float* __restrict__ conv_b, bf16* __restrict__ xc)
{
    int idx = blockIdx.x * 256 + threadIdx.x;
    int c = idx & (DINNER - 1);
    int row = idx >> 11;
    int l = row & (LSEQ - 1);
    float w0 = conv_w[c * 4 + 0];
    float w1 = conv_w[c * 4 + 1];
    float w2 = conv_w[c * 4 + 2];
    float w3 = conv_w[c * 4 + 3];
    const bf16* xr = xz + (size_t)row * (2 * DINNER) + c;
    float acc = conv_b[c] + (float)xr[0] * w3;
    if (l >= 1) acc += (float)xr[-1 * 2 * DINNER] * w2;
    if (l >= 2) acc += (float)xr[-2 * 2 * DINNER] * w1;
    if (l >= 3) acc += (float)xr[-3 * 2 * DINNER] * w0;
    float s = acc / (1.0f + __expf(-acc));
    xc[idx] = (bf16)s;
}

// ---------------------------------------------------------------------------
// xdbl[:, :64] fp32 -> dt bf16 packed [NROWS][64]
// ---------------------------------------------------------------------------
__global__ __launch_bounds__(256) void dtconv_kernel(
    const float* __restrict__ xdbl, bf16* __restrict__ dt)
{
    int idx = blockIdx.x * 256 + threadIdx.x;   // NROWS*64
    int row = idx >> 6, j = idx & 63;
    dt[idx] = (bf16)xdbl[(size_t)row * XROW + j];
}

// ---------------------------------------------------------------------------
// Selective scan. Block = 16 channels x 16 states. 256 blocks.
// ---------------------------------------------------------------------------
#define SCAN_T 64
__global__ __launch_bounds__(256) void scan_kernel(
    const float* __restrict__ delta,  // [NROWS][DINNER] fp32
    const bf16* __restrict__ xc,      // [NROWS][DINNER] bf16
    const float* __restrict__ xdbl,   // [NROWS][XROW]; B at 64, C at 80
    const float* __restrict__ A,      // [DINNER][DSTATE]
    float* __restrict__ y)            // [NROWS][DINNER]
{
    __shared__ float sB[SCAN_T][16];
    __shared__ float sC[SCAN_T][16];
    __shared__ float sD[SCAN_T][16];
    __shared__ float sX[SCAN_T][16];
    int b = blockIdx.x >> 7;
    int d_base = (blockIdx.x & 127) << 4;
    int tid = threadIdx.x;
    int ch = tid >> 4, n = tid & 15;
    int d = d_base + ch;
    float A_dn = A[d * DSTATE + n];
    float state = 0.0f;

    for (int l0 = 0; l0 < LSEQ; l0 += SCAN_T) {
        __syncthreads();
        #pragma unroll
        for (int i = 0; i < 4; ++i) {
            int idx = tid + i * 256;
            int lt = idx >> 4;
            int j = idx & 15;
            size_t rowoff = (size_t)(b * LSEQ + l0 + lt);
            sB[lt][j] = xdbl[rowoff * XROW + DTRANK + j];
            sC[lt][j] = xdbl[rowoff * XROW + DTRANK + DSTATE + j];
            sD[lt][j] = delta[rowoff * DINNER + d_base + j];
            sX[lt][j] = (float)xc[rowoff * DINNER + d_base + j];
        }
        __syncthreads();
        for (int lt = 0; lt < SCAN_T; ++lt) {
            float dv = sD[lt][ch];
            float xv = sX[lt][ch];
            float Bv = sB[lt][n];
            float Cv = sC[lt][n];
            float dA = __expf(dv * A_dn);
            state = dA * state + dv * xv * Bv;
            float prod = state * Cv;
            prod += __shfl_xor(prod, 1);
            prod += __shfl_xor(prod, 2);
            prod += __shfl_xor(prod, 4);
            prod += __shfl_xor(prod, 8);
            if (n == 0) y[(size_t)(b * LSEQ + l0 + lt) * DINNER + d] = prod;
        }
    }
}

// ---------------------------------------------------------------------------
// y_bf = bf16((ys + xc*D[c]) * silu(res)),  res = xz[:, 2048+c]
// ---------------------------------------------------------------------------
__global__ __launch_bounds__(256) void ymod_kernel(
    const float* __restrict__ ys, const bf16* __restrict__ xc,
    const bf16* __restrict__ xz, const float* __restrict__ Dp,
    bf16* __restrict__ ybf)
{
    int idx = blockIdx.x * 256 + threadIdx.x;
    int c = idx & (DINNER - 1);
    int row = idx >> 11;
    float res = (float)xz[(size_t)row * (2 * DINNER) + DINNER + c];
    float sres = res / (1.0f + __expf(-res));
    ybf[idx] = (bf16)((ys[idx] + (float)xc[idx] * Dp[c]) * sres);
}

// ---------------------------------------------------------------------------
extern "C" void kernel_launch(void* const* d_in, const int* in_sizes, int n_in,
                              void* d_out, int out_size, void* d_ws, size_t ws_size,
                              hipStream_t stream)
{
    const float* x0     = (const float*)d_in[0];
    const float* norm_w = (const float*)d_in[1];
    const float* W_in   = (const float*)d_in[2];   // [1024,4096]
    const float* conv_w = (const float*)d_in[3];
    const float* conv_b = (const float*)d_in[4];
    const float* W_x    = (const float*)d_in[5];   // [2048,96]
    const float* W_dt   = (const float*)d_in[6];   // [64,2048]
    const float* b_dt   = (const float*)d_in[7];
    const float* A      = (const float*)d_in[8];
    const float* Dp     = (const float*)d_in[9];
    const float* W_out  = (const float*)d_in[10];  // [2048,1024]
    float* out = (float*)d_out;

    // Workspace layout (~82 MB)
    char* p = (char*)d_ws;
    bf16*  xz_bf = (bf16*)p;            p += (size_t)NROWS * 2 * DINNER * 2; // 16MB
    float* xdbl  = (float*)p;           p += (size_t)NROWS * XROW * 4;       // 1MB
    float* delta = (float*)p;           p += (size_t)NROWS * DINNER * 4;     // 16MB
    float* ysb   = (float*)p;           p += (size_t)NROWS * DINNER * 4;     // 16MB
    bf16*  h_bf  = (bf16*)p;            p += (size_t)NROWS * DMODEL * 2;     // 4MB
    bf16*  xc_bf = (bf16*)p;            p += (size_t)NROWS * DINNER * 2;     // 8MB
    bf16*  y_bf  = (bf16*)p;            p += (size_t)NROWS * DINNER * 2;     // 8MB
    bf16*  WinT  = (bf16*)p;            p += (size_t)(2*DINNER) * DMODEL * 2;// 8MB
    bf16*  WxT   = (bf16*)p;            p += (size_t)XROW * DINNER * 2;      // 0.5MB
    bf16*  WdtT  = (bf16*)p;            p += (size_t)DINNER * DTRANK * 2;    // 0.25MB
    bf16*  WoutT = (bf16*)p;            p += (size_t)DMODEL * DINNER * 2;    // 4MB
    bf16*  dt_bf = (bf16*)p;            p += (size_t)NROWS * DTRANK * 2;     // 0.25MB

    // Weight conversions (transposed bf16)
    transpose_bf16_kernel<<<dim3(128, 32), 256, 0, stream>>>(W_in,  WinT,  DMODEL, 2*DINNER, 2*DINNER);
    transpose_bf16_kernel<<<dim3(4, 64),   256, 0, stream>>>(W_x,   WxT,   DINNER, 96, XROW);
    transpose_bf16_kernel<<<dim3(64, 2),   256, 0, stream>>>(W_dt,  WdtT,  DTRANK, DINNER, DINNER);
    transpose_bf16_kernel<<<dim3(32, 64),  256, 0, stream>>>(W_out, WoutT, DINNER, DMODEL, DMODEL);

    // 1. RMSNorm -> h bf16
    rmsnorm_kernel<<<NROWS, 256, 0, stream>>>(x0, norm_w, h_bf);

    // 2. xz = h @ W_in   [2048,1024]x[1024,4096] -> bf16
    gemm_bf16_kernel<0, true><<<dim3(32, 16, 1), 256, 0, stream>>>(
        h_bf, DMODEL, WinT, DMODEL, xz_bf, 2*DINNER, DMODEL, nullptr, nullptr, 0);

    // 3. causal conv + silu -> xc bf16
    conv_silu_kernel<<<(NROWS * DINNER) / 256, 256, 0, stream>>>(xz_bf, conv_w, conv_b, xc_bf);

    // 4. xdbl = xc @ W_x  (split-K=8, atomic fp32, N padded to 128)
    hipMemsetAsync(xdbl, 0, (size_t)NROWS * XROW * 4, stream);
    gemm_bf16_kernel<3, false><<<dim3(1, 16, 8), 256, 0, stream>>>(
        xc_bf, DINNER, WxT, DINNER, xdbl, XROW, DINNER / 8, nullptr, nullptr, 0);

    // 4b. dt columns -> bf16
    dtconv_kernel<<<(NROWS * DTRANK) / 256, 256, 0, stream>>>(xdbl, dt_bf);

    // 5. delta = softplus(dt @ W_dt + b_dt)  [2048,64]x[64,2048] -> fp32
    gemm_bf16_kernel<1, false><<<dim3(16, 16, 1), 256, 0, stream>>>(
        dt_bf, DTRANK, WdtT, DTRANK, delta, DINNER, DTRANK, b_dt, nullptr, 0);

    // 6. selective scan -> ys fp32
    scan_kernel<<<BATCH * (DINNER / 16), 256, 0, stream>>>(delta, xc_bf, xdbl, A, ysb);

    // 7. y = (ys + xc*D) * silu(res) -> bf16
    ymod_kernel<<<(NROWS * DINNER) / 256, 256, 0, stream>>>(ysb, xc_bf, xz_bf, Dp, y_bf);

    // 8. out = x0 + y @ W_out  [2048,2048]x[2048,1024] -> fp32
    gemm_bf16_kernel<2, false><<<dim3(8, 16, 1), 256, 0, stream>>>(
        y_bf, DINNER, WoutT, DINNER, out, DMODEL, DINNER, nullptr, x0, DMODEL);
}

// Round 3
// 306.226 us; speedup vs baseline: 4.3666x; 1.6139x over previous
//
#include <hip/hip_runtime.h>
#include <hip/hip_bf16.h>
#include <math.h>

// Problem constants
#define BATCH 2
#define LSEQ 1024
#define DMODEL 1024
#define DINNER 2048
#define DSTATE 16
#define DTRANK 64
#define NROWS (BATCH * LSEQ)   // 2048 token rows
#define XROW 128               // padded xdbl row stride (96 -> 128)
#define NC 32                  // scan chunks
#define TCH (LSEQ / NC)        // 32 timesteps per chunk

typedef __bf16 bf16;
typedef __attribute__((ext_vector_type(8))) __bf16 bf16x8;
typedef __attribute__((ext_vector_type(4))) float floatx4;

// ---------------------------------------------------------------------------
// bf16 MFMA GEMM, m97-style: 128x128 tile, BK=32, global_load_lds width-16.
// MODE 0: C = acc            MODE 1: C = softplus(acc + bias[n])
// MODE 2: C = acc + resid    MODE 3: atomicAdd(C, acc)  (split-K over blockIdx.z)
// ---------------------------------------------------------------------------
#define TM 128
#define TN 128
#define TK 32

__device__ __forceinline__ void glds16(const bf16* g, bf16* l) {
    __builtin_amdgcn_global_load_lds(
        (const __attribute__((address_space(1))) void*)g,
        (__attribute__((address_space(3))) void*)l, 16, 0, 0);
}

template<int MODE, bool BF16OUT>
__global__ __launch_bounds__(256) void gemm_bf16_kernel(
    const bf16* __restrict__ A, int lda,
    const bf16* __restrict__ Bt, int ldb,
    void* __restrict__ Cv, int ldc,
    int Ksplit,
    const float* __restrict__ bias,
    const float* __restrict__ resid, int ldr)
{
    __shared__ __attribute__((aligned(16))) bf16 As[TM * TK];
    __shared__ __attribute__((aligned(16))) bf16 Bs[TN * TK];

    const int tid  = threadIdx.x;
    const int lane = tid & 63;
    const int wave = tid >> 6;       // 4 waves: 2x2 grid of 64x64
    const int l15  = lane & 15;
    const int quad = lane >> 4;
    const int wm   = (wave >> 1) * 64;
    const int wn   = (wave & 1) * 64;

    const int row0 = blockIdx.y * TM;
    const int col0 = blockIdx.x * TN;
    const long kbase = (long)blockIdx.z * Ksplit;

    const int c0   = wave * 64 + lane;
    const int crow = c0 >> 2;
    const int ckq  = (c0 & 3) * 8;

    const bf16* gA0 = A  + (size_t)(row0 + crow) * lda + kbase + ckq;
    const bf16* gA1 = gA0 + (size_t)64 * lda;
    const bf16* gB0 = Bt + (size_t)(col0 + crow) * ldb + kbase + ckq;
    const bf16* gB1 = gB0 + (size_t)64 * ldb;

    bf16* lA0 = As + wave * 64 * 8;
    bf16* lA1 = As + (256 + wave * 64) * 8;
    bf16* lB0 = Bs + wave * 64 * 8;
    bf16* lB1 = Bs + (256 + wave * 64) * 8;

    floatx4 acc[4][4];
    #pragma unroll
    for (int i = 0; i < 4; ++i)
        #pragma unroll
        for (int j = 0; j < 4; ++j)
            acc[i][j] = (floatx4){0.f, 0.f, 0.f, 0.f};

    const int kiters = Ksplit / TK;
    for (int kk = 0; kk < kiters; ++kk) {
        __syncthreads();
        glds16(gA0, lA0);
        glds16(gA1, lA1);
        glds16(gB0, lB0);
        glds16(gB1, lB1);
        gA0 += TK; gA1 += TK; gB0 += TK; gB1 += TK;
        __syncthreads();

        bf16x8 af[4], bfr[4];
        #pragma unroll
        for (int i = 0; i < 4; ++i)
            af[i] = *(const bf16x8*)&As[(wm + i * 16 + l15) * TK + quad * 8];
        #pragma unroll
        for (int j = 0; j < 4; ++j)
            bfr[j] = *(const bf16x8*)&Bs[(wn + j * 16 + l15) * TK + quad * 8];
        #pragma unroll
        for (int i = 0; i < 4; ++i)
            #pragma unroll
            for (int j = 0; j < 4; ++j)
                acc[i][j] = __builtin_amdgcn_mfma_f32_16x16x32_bf16(
                                af[i], bfr[j], acc[i][j], 0, 0, 0);
    }

    #pragma unroll
    for (int i = 0; i < 4; ++i) {
        #pragma unroll
        for (int j = 0; j < 4; ++j) {
            const int gn = col0 + wn + j * 16 + l15;
            #pragma unroll
            for (int r = 0; r < 4; ++r) {
                const int gm = row0 + wm + i * 16 + quad * 4 + r;
                float v = acc[i][j][r];
                if (MODE == 1) {
                    v += bias[gn];
                    v = (v > 20.0f) ? v : log1pf(__expf(v));
                }
                if (MODE == 2) v += resid[(size_t)gm * ldr + gn];
                if (MODE == 3) {
                    atomicAdd(&((float*)Cv)[(size_t)gm * ldc + gn], v);
                } else if (BF16OUT) {
                    ((bf16*)Cv)[(size_t)gm * ldc + gn] = (bf16)v;
                } else {
                    ((float*)Cv)[(size_t)gm * ldc + gn] = v;
                }
            }
        }
    }
}

// ---------------------------------------------------------------------------
// Transpose-convert: W [K][N] fp32 -> Wt [Npad][K] bf16, zero-fill n>=N.
// ---------------------------------------------------------------------------
__global__ __launch_bounds__(256) void transpose_bf16_kernel(
    const float* __restrict__ W, bf16* __restrict__ Wt,
    int K, int N, int Npad)
{
    __shared__ float tile[32][33];
    const int n0 = blockIdx.x * 32;
    const int k0 = blockIdx.y * 32;
    const int tx = threadIdx.x & 31;
    const int ty = threadIdx.x >> 5;
    #pragma unroll
    for (int i = 0; i < 32; i += 8) {
        int k = k0 + ty + i, n = n0 + tx;
        tile[ty + i][tx] = (k < K && n < N) ? W[(size_t)k * N + n] : 0.0f;
    }
    __syncthreads();
    #pragma unroll
    for (int i = 0; i < 32; i += 8) {
        int n = n0 + ty + i, k = k0 + tx;
        if (n < Npad && k < K)
            Wt[(size_t)n * K + k] = (bf16)tile[tx][ty + i];
    }
}

// ---------------------------------------------------------------------------
// RMSNorm -> bf16 h. One block per token row.
// ---------------------------------------------------------------------------
__global__ __launch_bounds__(256) void rmsnorm_kernel(
    const float* __restrict__ x, const float* __restrict__ w,
    bf16* __restrict__ h)
{
    int row = blockIdx.x;
    int tid = threadIdx.x;
    const float* xr = x + (size_t)row * DMODEL;
    float4 v = *(const float4*)(xr + tid * 4);
    float ss = v.x * v.x + v.y * v.y + v.z * v.z + v.w * v.w;
    #pragma unroll
    for (int m = 32; m >= 1; m >>= 1) ss += __shfl_xor(ss, m);
    __shared__ float ws[4];
    if ((tid & 63) == 0) ws[tid >> 6] = ss;
    __syncthreads();
    float total = ws[0] + ws[1] + ws[2] + ws[3];
    float scale = rsqrtf(total * (1.0f / DMODEL) + 1e-5f);
    float4 wv = *(const float4*)(w + tid * 4);
    union { bf16 b[4]; uint2 u; } pk;
    pk.b[0] = (bf16)(v.x * scale * wv.x);
    pk.b[1] = (bf16)(v.y * scale * wv.y);
    pk.b[2] = (bf16)(v.z * scale * wv.z);
    pk.b[3] = (bf16)(v.w * scale * wv.w);
    *(uint2*)(h + (size_t)row * DMODEL + tid * 4) = pk.u;
}

// ---------------------------------------------------------------------------
// Causal depthwise conv (K=4) + bias + SiLU. x half of xz (bf16, stride 4096).
// ---------------------------------------------------------------------------
__global__ __launch_bounds__(256) void conv_silu_kernel(
    const bf16* __restrict__ xz, const float* __restrict__ conv_w,
    const float* __restrict__ conv_b, bf16* __restrict__ xc)
{
    int idx = blockIdx.x * 256 + threadIdx.x;
    int c = idx & (DINNER - 1);
    int row = idx >> 11;
    int l = row & (LSEQ - 1);
    float w0 = conv_w[c * 4 + 0];
    float w1 = conv_w[c * 4 + 1];
    float w2 = conv_w[c * 4 + 2];
    float w3 = conv_w[c * 4 + 3];
    const bf16* xr = xz + (size_t)row * (2 * DINNER) + c;
    float acc = conv_b[c] + (float)xr[0] * w3;
    if (l >= 1) acc += (float)xr[-1 * 2 * DINNER] * w2;
    if (l >= 2) acc += (float)xr[-2 * 2 * DINNER] * w1;
    if (l >= 3) acc += (float)xr[-3 * 2 * DINNER] * w0;
    float s = acc / (1.0f + __expf(-acc));
    xc[idx] = (bf16)s;
}

// ---------------------------------------------------------------------------
// xdbl[:, :64] fp32 -> dt bf16 packed [NROWS][64]
// ---------------------------------------------------------------------------
__global__ __launch_bounds__(256) void dtconv_kernel(
    const float* __restrict__ xdbl, bf16* __restrict__ dt)
{
    int idx = blockIdx.x * 256 + threadIdx.x;
    int row = idx >> 6, j = idx & 63;
    dt[idx] = (bf16)xdbl[(size_t)row * XROW + j];
}

// ---------------------------------------------------------------------------
// Chunked selective scan.
// Lane = (b, chunk, d); 16 states per lane in registers, no cross-lane ops.
// Phase 1 (FINAL=false): from zero init compute P[n] = prod(dA), S[n] = local
//   final state; store to Pbuf/Sbuf [B][NC][D][16].
// Combine: per (b,d,n), serially convert (P,S) per chunk into the chunk's
//   true initial state (written back into Sbuf).
// Phase 2 (FINAL=true): re-run chunk from true init, emit
//   ybf = (y + x*D) * silu(res)  (ymod fused).
// ---------------------------------------------------------------------------
template<bool FINAL>
__global__ __launch_bounds__(256) void scan_chunk_kernel(
    const float* __restrict__ delta,  // [NROWS][DINNER] fp32
    const bf16* __restrict__ xc,      // [NROWS][DINNER]
    const float* __restrict__ xdbl,   // [NROWS][XROW]; B at 64, C at 80
    const float* __restrict__ A,      // [DINNER][DSTATE]
    float* __restrict__ Pbuf,         // [B][NC][DINNER][16]
    float* __restrict__ Sbuf,         // [B][NC][DINNER][16]
    const bf16* __restrict__ xz,      // res at col DINNER+d, stride 2*DINNER
    const float* __restrict__ Dp,     // [DINNER]
    bf16* __restrict__ ybf)           // [NROWS][DINNER]
{
    __shared__ float sBC[TCH][32];    // [t][0:16]=B, [t][16:32]=C
    const int tid   = threadIdx.x;
    const int chunk = blockIdx.x;
    const int d     = blockIdx.y * 256 + tid;
    const int b     = blockIdx.z;
    const int row0  = b * LSEQ + chunk * TCH;

    // stage B,C for this chunk: 32 rows x 32 floats, one float4 per thread
    {
        int t = tid >> 3, c4 = (tid & 7) * 4;
        *(float4*)&sBC[t][c4] =
            *(const float4*)&xdbl[(size_t)(row0 + t) * XROW + DTRANK + c4];
    }

    float Ad[16];
    #pragma unroll
    for (int j = 0; j < 4; ++j) {
        float4 av = *(const float4*)&A[(size_t)d * DSTATE + j * 4];
        Ad[j*4+0] = av.x; Ad[j*4+1] = av.y; Ad[j*4+2] = av.z; Ad[j*4+3] = av.w;
    }

    const size_t psoff = ((size_t)(b * NC + chunk) * DINNER + d) * DSTATE;
    float S[16], P[16];
    if (FINAL) {
        #pragma unroll
        for (int j = 0; j < 4; ++j) {
            float4 sv = *(const float4*)&Sbuf[psoff + j * 4];
            S[j*4+0] = sv.x; S[j*4+1] = sv.y; S[j*4+2] = sv.z; S[j*4+3] = sv.w;
        }
    } else {
        #pragma unroll
        for (int n = 0; n < 16; ++n) { S[n] = 0.0f; P[n] = 1.0f; }
    }
    float Dpd = FINAL ? Dp[d] : 0.0f;

    __syncthreads();

    #pragma unroll 2
    for (int t = 0; t < TCH; ++t) {
        const size_t row = (size_t)(row0 + t);
        float dv = delta[row * DINNER + d];
        float xv = (float)xc[row * DINNER + d];
        float u  = dv * xv;
        float yp[4] = {0.f, 0.f, 0.f, 0.f};
        #pragma unroll
        for (int n = 0; n < 16; ++n) {
            float dA = __expf(dv * Ad[n]);
            S[n] = dA * S[n] + u * sBC[t][n];
            if (FINAL) {
                yp[n & 3] += S[n] * sBC[t][16 + n];
            } else {
                P[n] *= dA;
            }
        }
        if (FINAL) {
            float y = (yp[0] + yp[1]) + (yp[2] + yp[3]);
            float res = (float)xz[row * (2 * DINNER) + DINNER + d];
            float sres = res / (1.0f + __expf(-res));
            ybf[row * DINNER + d] = (bf16)((y + xv * Dpd) * sres);
        }
    }

    if (!FINAL) {
        #pragma unroll
        for (int j = 0; j < 4; ++j) {
            *(float4*)&Pbuf[psoff + j * 4] =
                (float4){P[j*4+0], P[j*4+1], P[j*4+2], P[j*4+3]};
            *(float4*)&Sbuf[psoff + j * 4] =
                (float4){S[j*4+0], S[j*4+1], S[j*4+2], S[j*4+3]};
        }
    }
}

// Per-(b,d,n) serial combine over chunks: Sbuf[k] <- true initial state.
__global__ __launch_bounds__(256) void scan_combine_kernel(
    const float* __restrict__ Pbuf, float* __restrict__ Sbuf)
{
    int gid = blockIdx.x * 256 + threadIdx.x;   // B * DINNER * 16 = 65536
    int b = gid >> 15;
    int dn = gid & 32767;
    float carry = 0.0f;
    for (int k = 0; k < NC; ++k) {
        size_t off = ((size_t)(b * NC + k) << 15) + dn;
        float pk = Pbuf[off];
        float sk = Sbuf[off];
        Sbuf[off] = carry;
        carry = pk * carry + sk;
    }
}

// ---------------------------------------------------------------------------
extern "C" void kernel_launch(void* const* d_in, const int* in_sizes, int n_in,
                              void* d_out, int out_size, void* d_ws, size_t ws_size,
                              hipStream_t stream)
{
    const float* x0     = (const float*)d_in[0];
    const float* norm_w = (const float*)d_in[1];
    const float* W_in   = (const float*)d_in[2];   // [1024,4096]
    const float* conv_w = (const float*)d_in[3];
    const float* conv_b = (const float*)d_in[4];
    const float* W_x    = (const float*)d_in[5];   // [2048,96]
    const float* W_dt   = (const float*)d_in[6];   // [64,2048]
    const float* b_dt   = (const float*)d_in[7];
    const float* A      = (const float*)d_in[8];
    const float* Dp     = (const float*)d_in[9];
    const float* W_out  = (const float*)d_in[10];  // [2048,1024]
    float* out = (float*)d_out;

    // Workspace layout (~82 MB)
    char* p = (char*)d_ws;
    bf16*  xz_bf = (bf16*)p;            p += (size_t)NROWS * 2 * DINNER * 2; // 16MB
    float* xdbl  = (float*)p;           p += (size_t)NROWS * XROW * 4;       // 1MB
    float* delta = (float*)p;           p += (size_t)NROWS * DINNER * 4;     // 16MB
    float* Pbuf  = (float*)p;           p += (size_t)BATCH * NC * DINNER * 16 * 4; // 8MB
    float* Sbuf  = (float*)p;           p += (size_t)BATCH * NC * DINNER * 16 * 4; // 8MB
    bf16*  h_bf  = (bf16*)p;            p += (size_t)NROWS * DMODEL * 2;     // 4MB
    bf16*  xc_bf = (bf16*)p;            p += (size_t)NROWS * DINNER * 2;     // 8MB
    bf16*  y_bf  = (bf16*)p;            p += (size_t)NROWS * DINNER * 2;     // 8MB
    bf16*  WinT  = (bf16*)p;            p += (size_t)(2*DINNER) * DMODEL * 2;// 8MB
    bf16*  WxT   = (bf16*)p;            p += (size_t)XROW * DINNER * 2;      // 0.5MB
    bf16*  WdtT  = (bf16*)p;            p += (size_t)DINNER * DTRANK * 2;    // 0.25MB
    bf16*  WoutT = (bf16*)p;            p += (size_t)DMODEL * DINNER * 2;    // 4MB
    bf16*  dt_bf = (bf16*)p;            p += (size_t)NROWS * DTRANK * 2;     // 0.25MB

    // Weight conversions (transposed bf16)
    transpose_bf16_kernel<<<dim3(128, 32), 256, 0, stream>>>(W_in,  WinT,  DMODEL, 2*DINNER, 2*DINNER);
    transpose_bf16_kernel<<<dim3(4, 64),   256, 0, stream>>>(W_x,   WxT,   DINNER, 96, XROW);
    transpose_bf16_kernel<<<dim3(64, 2),   256, 0, stream>>>(W_dt,  WdtT,  DTRANK, DINNER, DINNER);
    transpose_bf16_kernel<<<dim3(32, 64),  256, 0, stream>>>(W_out, WoutT, DINNER, DMODEL, DMODEL);

    // 1. RMSNorm -> h bf16
    rmsnorm_kernel<<<NROWS, 256, 0, stream>>>(x0, norm_w, h_bf);

    // 2. xz = h @ W_in   [2048,1024]x[1024,4096] -> bf16
    gemm_bf16_kernel<0, true><<<dim3(32, 16, 1), 256, 0, stream>>>(
        h_bf, DMODEL, WinT, DMODEL, xz_bf, 2*DINNER, DMODEL, nullptr, nullptr, 0);

    // 3. causal conv + silu -> xc bf16
    conv_silu_kernel<<<(NROWS * DINNER) / 256, 256, 0, stream>>>(xz_bf, conv_w, conv_b, xc_bf);

    // 4. xdbl = xc @ W_x  (split-K=8, atomic fp32, N padded to 128)
    hipMemsetAsync(xdbl, 0, (size_t)NROWS * XROW * 4, stream);
    gemm_bf16_kernel<3, false><<<dim3(1, 16, 8), 256, 0, stream>>>(
        xc_bf, DINNER, WxT, DINNER, xdbl, XROW, DINNER / 8, nullptr, nullptr, 0);

    // 4b. dt columns -> bf16
    dtconv_kernel<<<(NROWS * DTRANK) / 256, 256, 0, stream>>>(xdbl, dt_bf);

    // 5. delta = softplus(dt @ W_dt + b_dt)  [2048,64]x[64,2048] -> fp32
    gemm_bf16_kernel<1, false><<<dim3(16, 16, 1), 256, 0, stream>>>(
        dt_bf, DTRANK, WdtT, DTRANK, delta, DINNER, DTRANK, b_dt, nullptr, 0);

    // 6. chunked selective scan (+ fused ymod) -> y_bf
    dim3 sgrid(NC, DINNER / 256, BATCH);
    scan_chunk_kernel<false><<<sgrid, 256, 0, stream>>>(
        delta, xc_bf, xdbl, A, Pbuf, Sbuf, nullptr, nullptr, nullptr);
    scan_combine_kernel<<<(BATCH * DINNER * DSTATE) / 256, 256, 0, stream>>>(Pbuf, Sbuf);
    scan_chunk_kernel<true><<<sgrid, 256, 0, stream>>>(
        delta, xc_bf, xdbl, A, Pbuf, Sbuf, xz_bf, Dp, y_bf);

    // 7. out = x0 + y @ W_out  [2048,2048]x[2048,1024] -> fp32
    gemm_bf16_kernel<2, false><<<dim3(8, 16, 1), 256, 0, stream>>>(
        y_bf, DINNER, WoutT, DINNER, out, DMODEL, DINNER, nullptr, x0, DMODEL);
}

// Round 4
// 278.461 us; speedup vs baseline: 4.8020x; 1.0997x over previous
//
#include <hip/hip_runtime.h>
#include <hip/hip_bf16.h>
#include <math.h>

// Problem constants
#define BATCH 2
#define LSEQ 1024
#define DMODEL 1024
#define DINNER 2048
#define DSTATE 16
#define DTRANK 64
#define NROWS (BATCH * LSEQ)   // 2048 token rows
#define XROW 128               // padded x_proj width (96 -> 128)
#define NC 32                  // scan chunks
#define TCH (LSEQ / NC)        // 32 timesteps per chunk

typedef __bf16 bf16;
typedef __attribute__((ext_vector_type(8))) __bf16 bf16x8;
typedef __attribute__((ext_vector_type(4))) float floatx4;

// ---------------------------------------------------------------------------
// bf16 MFMA GEMM. TM=128, templated TN/BK. global_load_lds width-16 staging
// with XOR-swizzled K-chunks: element (r, kc*8..) stored at LDS chunk
// (kc ^ (r&7)) -> fragment ds_read_b128 becomes 2-way (free) instead of 8-way.
// MODE 0: C = acc                MODE 1: C = softplus(acc + bias[n])
// MODE 2: C = acc + resid[gm*ldr+gn]
// MODE 4: C[z*ldr + gm*ldc+gn] = acc   (split-K partials, ldr = slice stride)
// ---------------------------------------------------------------------------
template<int MODE, bool BF16OUT, int TN_, int BK_>
__global__ __launch_bounds__(256) void gemm_bf16_kernel(
    const bf16* __restrict__ A, int lda,
    const bf16* __restrict__ Bt, int ldb,
    void* __restrict__ Cv, int ldc,
    int Ksplit,
    const float* __restrict__ bias,
    const float* __restrict__ resid, int ldr)
{
    constexpr int TMc  = 128;
    constexpr int CA   = BK_ / 8;                  // chunks per row (8 for BK=64)
    constexpr int ISSA = TMc * BK_ * 2 / 4096;     // 4-KB issues for A
    constexpr int ISSB = TN_ * BK_ * 2 / 4096;
    constexpr int NB   = TN_ / 32;                 // B frags per wave
    constexpr int NH   = BK_ / 32;                 // K halves per iter

    __shared__ __attribute__((aligned(16))) bf16 As[TMc * BK_];
    __shared__ __attribute__((aligned(16))) bf16 Bs[TN_ * BK_];

    const int tid  = threadIdx.x;
    const int lane = tid & 63;
    const int wave = tid >> 6;       // 2x2 wave grid
    const int l15  = lane & 15;
    const int quad = lane >> 4;
    const int wm   = (wave >> 1) * 64;
    const int wn   = (wave & 1) * (TN_ / 2);

    const int row0 = blockIdx.y * TMc;
    const int col0 = blockIdx.x * TN_;
    const long kbase = (long)blockIdx.z * Ksplit;

    // staging pointers: chunk c = i*256 + wave*64 + lane
    const bf16* gA[ISSA]; bf16* lA[ISSA];
    const bf16* gB[ISSB]; bf16* lB[ISSB];
    #pragma unroll
    for (int i = 0; i < ISSA; ++i) {
        int c = i * 256 + wave * 64 + lane;
        int r = c / CA;
        int kc = (c % CA) ^ (r % CA);              // fetch swizzled chunk
        gA[i] = A + (size_t)(row0 + r) * lda + kbase + kc * 8;
        lA[i] = As + (size_t)(i * 256 + wave * 64) * 8;
    }
    #pragma unroll
    for (int i = 0; i < ISSB; ++i) {
        int c = i * 256 + wave * 64 + lane;
        int r = c / CA;
        int kc = (c % CA) ^ (r % CA);
        gB[i] = Bt + (size_t)(col0 + r) * ldb + kbase + kc * 8;
        lB[i] = Bs + (size_t)(i * 256 + wave * 64) * 8;
    }

    floatx4 acc[4][NB];
    #pragma unroll
    for (int i = 0; i < 4; ++i)
        #pragma unroll
        for (int j = 0; j < NB; ++j)
            acc[i][j] = (floatx4){0.f, 0.f, 0.f, 0.f};

    const int kiters = Ksplit / BK_;
    for (int kk = 0; kk < kiters; ++kk) {
        __syncthreads();
        #pragma unroll
        for (int i = 0; i < ISSA; ++i) {
            __builtin_amdgcn_global_load_lds(
                (const __attribute__((address_space(1))) void*)gA[i],
                (__attribute__((address_space(3))) void*)lA[i], 16, 0, 0);
            gA[i] += BK_;
        }
        #pragma unroll
        for (int i = 0; i < ISSB; ++i) {
            __builtin_amdgcn_global_load_lds(
                (const __attribute__((address_space(1))) void*)gB[i],
                (__attribute__((address_space(3))) void*)lB[i], 16, 0, 0);
            gB[i] += BK_;
        }
        __syncthreads();

        #pragma unroll
        for (int h = 0; h < NH; ++h) {
            bf16x8 af[4], bfr[NB];
            #pragma unroll
            for (int i = 0; i < 4; ++i) {
                int r = wm + i * 16 + l15;
                af[i] = *(const bf16x8*)&As[(size_t)r * BK_ +
                          (((h * 4 + quad) ^ (r % CA)) * 8)];
            }
            #pragma unroll
            for (int j = 0; j < NB; ++j) {
                int r = wn + j * 16 + l15;
                bfr[j] = *(const bf16x8*)&Bs[(size_t)r * BK_ +
                           (((h * 4 + quad) ^ (r % CA)) * 8)];
            }
            #pragma unroll
            for (int i = 0; i < 4; ++i)
                #pragma unroll
                for (int j = 0; j < NB; ++j)
                    acc[i][j] = __builtin_amdgcn_mfma_f32_16x16x32_bf16(
                                    af[i], bfr[j], acc[i][j], 0, 0, 0);
        }
    }

    // epilogue: D frag mapping col=lane&15, row=quad*4+reg
    #pragma unroll
    for (int i = 0; i < 4; ++i) {
        #pragma unroll
        for (int j = 0; j < NB; ++j) {
            const int gn = col0 + wn + j * 16 + l15;
            #pragma unroll
            for (int r = 0; r < 4; ++r) {
                const int gm = row0 + wm + i * 16 + quad * 4 + r;
                float v = acc[i][j][r];
                if (MODE == 1) {
                    v += bias[gn];
                    v = (v > 20.0f) ? v : log1pf(__expf(v));
                }
                if (MODE == 2) v += resid[(size_t)gm * ldr + gn];
                if (MODE == 4) {
                    ((float*)Cv)[(size_t)blockIdx.z * ldr + (size_t)gm * ldc + gn] = v;
                } else if (BF16OUT) {
                    ((bf16*)Cv)[(size_t)gm * ldc + gn] = (bf16)v;
                } else {
                    ((float*)Cv)[(size_t)gm * ldc + gn] = v;
                }
            }
        }
    }
}

// ---------------------------------------------------------------------------
// Transpose-convert: W [K][N] fp32 -> Wt [Npad][K] bf16, zero-fill n>=N.
// ---------------------------------------------------------------------------
__global__ __launch_bounds__(256) void transpose_bf16_kernel(
    const float* __restrict__ W, bf16* __restrict__ Wt,
    int K, int N, int Npad)
{
    __shared__ float tile[32][33];
    const int n0 = blockIdx.x * 32;
    const int k0 = blockIdx.y * 32;
    const int tx = threadIdx.x & 31;
    const int ty = threadIdx.x >> 5;
    #pragma unroll
    for (int i = 0; i < 32; i += 8) {
        int k = k0 + ty + i, n = n0 + tx;
        tile[ty + i][tx] = (k < K && n < N) ? W[(size_t)k * N + n] : 0.0f;
    }
    __syncthreads();
    #pragma unroll
    for (int i = 0; i < 32; i += 8) {
        int n = n0 + ty + i, k = k0 + tx;
        if (n < Npad && k < K)
            Wt[(size_t)n * K + k] = (bf16)tile[tx][ty + i];
    }
}

// ---------------------------------------------------------------------------
// RMSNorm -> bf16 h. One block per token row.
// ---------------------------------------------------------------------------
__global__ __launch_bounds__(256) void rmsnorm_kernel(
    const float* __restrict__ x, const float* __restrict__ w,
    bf16* __restrict__ h)
{
    int row = blockIdx.x;
    int tid = threadIdx.x;
    const float* xr = x + (size_t)row * DMODEL;
    float4 v = *(const float4*)(xr + tid * 4);
    float ss = v.x * v.x + v.y * v.y + v.z * v.z + v.w * v.w;
    #pragma unroll
    for (int m = 32; m >= 1; m >>= 1) ss += __shfl_xor(ss, m);
    __shared__ float ws[4];
    if ((tid & 63) == 0) ws[tid >> 6] = ss;
    __syncthreads();
    float total = ws[0] + ws[1] + ws[2] + ws[3];
    float scale = rsqrtf(total * (1.0f / DMODEL) + 1e-5f);
    float4 wv = *(const float4*)(w + tid * 4);
    union { bf16 b[4]; uint2 u; } pk;
    pk.b[0] = (bf16)(v.x * scale * wv.x);
    pk.b[1] = (bf16)(v.y * scale * wv.y);
    pk.b[2] = (bf16)(v.z * scale * wv.z);
    pk.b[3] = (bf16)(v.w * scale * wv.w);
    *(uint2*)(h + (size_t)row * DMODEL + tid * 4) = pk.u;
}

// ---------------------------------------------------------------------------
// Causal depthwise conv (K=4) + bias + SiLU. x half of xz (bf16, stride 4096).
// ---------------------------------------------------------------------------
__global__ __launch_bounds__(256) void conv_silu_kernel(
    const bf16* __restrict__ xz, const float* __restrict__ conv_w,
    const float* __restrict__ conv_b, bf16* __restrict__ xc)
{
    int idx = blockIdx.x * 256 + threadIdx.x;
    int c = idx & (DINNER - 1);
    int row = idx >> 11;
    int l = row & (LSEQ - 1);
    float w0 = conv_w[c * 4 + 0];
    float w1 = conv_w[c * 4 + 1];
    float w2 = conv_w[c * 4 + 2];
    float w3 = conv_w[c * 4 + 3];
    const bf16* xr = xz + (size_t)row * (2 * DINNER) + c;
    float acc = conv_b[c] + (float)xr[0] * w3;
    if (l >= 1) acc += (float)xr[-1 * 2 * DINNER] * w2;
    if (l >= 2) acc += (float)xr[-2 * 2 * DINNER] * w1;
    if (l >= 3) acc += (float)xr[-3 * 2 * DINNER] * w0;
    float s = acc / (1.0f + __expf(-acc));
    xc[idx] = (bf16)s;
}

// ---------------------------------------------------------------------------
// Reduce x_proj split-K partials: sum 8 slices of [NROWS][128].
// cols 0..63 -> dt_bf (bf16), cols 64..95 -> BC fp32 [NROWS][32].
// ---------------------------------------------------------------------------
__global__ __launch_bounds__(256) void xproj_reduce_kernel(
    const float* __restrict__ Pw, bf16* __restrict__ dt,
    float* __restrict__ BC)
{
    int idx = blockIdx.x * 256 + threadIdx.x;   // NROWS*128
    int row = idx >> 7, c = idx & 127;
    float s = 0.0f;
    #pragma unroll
    for (int k = 0; k < 8; ++k)
        s += Pw[(size_t)k * NROWS * XROW + idx];
    if (c < 64) dt[(size_t)row * 64 + c] = (bf16)s;
    else if (c < 96) BC[(size_t)row * 32 + (c - 64)] = s;
}

// ---------------------------------------------------------------------------
// Chunked selective scan. Lane = (b, chunk, d); 16 states in registers.
// Phase 1: P = prod(dA), S = local final state. Combine: chunk-serial fixup.
// Phase 2: re-run from true init, fused ymod epilogue -> ybf.
// ---------------------------------------------------------------------------
template<bool FINAL>
__global__ __launch_bounds__(256) void scan_chunk_kernel(
    const float* __restrict__ delta,  // [NROWS][DINNER] fp32
    const bf16* __restrict__ xc,      // [NROWS][DINNER]
    const float* __restrict__ BC,     // [NROWS][32]: B then C
    const float* __restrict__ A,      // [DINNER][DSTATE]
    float* __restrict__ Pbuf,         // [B][NC][DINNER][16]
    float* __restrict__ Sbuf,         // [B][NC][DINNER][16]
    const bf16* __restrict__ xz,      // res at col DINNER+d, stride 2*DINNER
    const float* __restrict__ Dp,     // [DINNER]
    bf16* __restrict__ ybf)           // [NROWS][DINNER]
{
    __shared__ float sBC[TCH][32];
    const int tid   = threadIdx.x;
    const int chunk = blockIdx.x;
    const int d     = blockIdx.y * 256 + tid;
    const int b     = blockIdx.z;
    const int row0  = b * LSEQ + chunk * TCH;

    {
        int t = tid >> 3, c4 = (tid & 7) * 4;
        *(float4*)&sBC[t][c4] = *(const float4*)&BC[(size_t)(row0 + t) * 32 + c4];
    }

    float Ad[16];
    #pragma unroll
    for (int j = 0; j < 4; ++j) {
        float4 av = *(const float4*)&A[(size_t)d * DSTATE + j * 4];
        Ad[j*4+0] = av.x; Ad[j*4+1] = av.y; Ad[j*4+2] = av.z; Ad[j*4+3] = av.w;
    }

    const size_t psoff = ((size_t)(b * NC + chunk) * DINNER + d) * DSTATE;
    float S[16], P[16];
    if (FINAL) {
        #pragma unroll
        for (int j = 0; j < 4; ++j) {
            float4 sv = *(const float4*)&Sbuf[psoff + j * 4];
            S[j*4+0] = sv.x; S[j*4+1] = sv.y; S[j*4+2] = sv.z; S[j*4+3] = sv.w;
        }
    } else {
        #pragma unroll
        for (int n = 0; n < 16; ++n) { S[n] = 0.0f; P[n] = 1.0f; }
    }
    float Dpd = FINAL ? Dp[d] : 0.0f;

    __syncthreads();

    #pragma unroll 2
    for (int t = 0; t < TCH; ++t) {
        const size_t row = (size_t)(row0 + t);
        float dv = delta[row * DINNER + d];
        float xv = (float)xc[row * DINNER + d];
        float u  = dv * xv;
        float yp[4] = {0.f, 0.f, 0.f, 0.f};
        #pragma unroll
        for (int n = 0; n < 16; ++n) {
            float dA = __expf(dv * Ad[n]);
            S[n] = dA * S[n] + u * sBC[t][n];
            if (FINAL) {
                yp[n & 3] += S[n] * sBC[t][16 + n];
            } else {
                P[n] *= dA;
            }
        }
        if (FINAL) {
            float y = (yp[0] + yp[1]) + (yp[2] + yp[3]);
            float res = (float)xz[row * (2 * DINNER) + DINNER + d];
            float sres = res / (1.0f + __expf(-res));
            ybf[row * DINNER + d] = (bf16)((y + xv * Dpd) * sres);
        }
    }

    if (!FINAL) {
        #pragma unroll
        for (int j = 0; j < 4; ++j) {
            *(float4*)&Pbuf[psoff + j * 4] =
                (float4){P[j*4+0], P[j*4+1], P[j*4+2], P[j*4+3]};
            *(float4*)&Sbuf[psoff + j * 4] =
                (float4){S[j*4+0], S[j*4+1], S[j*4+2], S[j*4+3]};
        }
    }
}

// Per-(b,d,n) serial combine over chunks: Sbuf[k] <- true initial state.
__global__ __launch_bounds__(256) void scan_combine_kernel(
    const float* __restrict__ Pbuf, float* __restrict__ Sbuf)
{
    int gid = blockIdx.x * 256 + threadIdx.x;   // B * DINNER * 16 = 65536
    int b = gid >> 15;
    int dn = gid & 32767;
    float carry = 0.0f;
    for (int k = 0; k < NC; ++k) {
        size_t off = ((size_t)(b * NC + k) << 15) + dn;
        float pk = Pbuf[off];
        float sk = Sbuf[off];
        Sbuf[off] = carry;
        carry = pk * carry + sk;
    }
}

// ---------------------------------------------------------------------------
extern "C" void kernel_launch(void* const* d_in, const int* in_sizes, int n_in,
                              void* d_out, int out_size, void* d_ws, size_t ws_size,
                              hipStream_t stream)
{
    const float* x0     = (const float*)d_in[0];
    const float* norm_w = (const float*)d_in[1];
    const float* W_in   = (const float*)d_in[2];   // [1024,4096]
    const float* conv_w = (const float*)d_in[3];
    const float* conv_b = (const float*)d_in[4];
    const float* W_x    = (const float*)d_in[5];   // [2048,96]
    const float* W_dt   = (const float*)d_in[6];   // [64,2048]
    const float* b_dt   = (const float*)d_in[7];
    const float* A      = (const float*)d_in[8];
    const float* Dp     = (const float*)d_in[9];
    const float* W_out  = (const float*)d_in[10];  // [2048,1024]
    float* out = (float*)d_out;

    // Workspace layout (~82 MB)
    char* p = (char*)d_ws;
    bf16*  xz_bf = (bf16*)p;            p += (size_t)NROWS * 2 * DINNER * 2;       // 16MB
    float* Pw    = (float*)p;           p += (size_t)8 * NROWS * XROW * 4;         // 8MB
    float* BC    = (float*)p;           p += (size_t)NROWS * 32 * 4;               // 0.25MB
    float* delta = (float*)p;           p += (size_t)NROWS * DINNER * 4;           // 16MB
    float* Pbuf  = (float*)p;           p += (size_t)BATCH * NC * DINNER * 16 * 4; // 8MB
    float* Sbuf  = (float*)p;           p += (size_t)BATCH * NC * DINNER * 16 * 4; // 8MB
    bf16*  h_bf  = (bf16*)p;            p += (size_t)NROWS * DMODEL * 2;           // 4MB
    bf16*  xc_bf = (bf16*)p;            p += (size_t)NROWS * DINNER * 2;           // 8MB
    bf16*  y_bf  = (bf16*)p;            p += (size_t)NROWS * DINNER * 2;           // 8MB
    bf16*  WinT  = (bf16*)p;            p += (size_t)(2*DINNER) * DMODEL * 2;      // 8MB
    bf16*  WxT   = (bf16*)p;            p += (size_t)XROW * DINNER * 2;            // 0.5MB
    bf16*  WdtT  = (bf16*)p;            p += (size_t)DINNER * DTRANK * 2;          // 0.25MB
    bf16*  WoutT = (bf16*)p;            p += (size_t)DMODEL * DINNER * 2;          // 4MB
    bf16*  dt_bf = (bf16*)p;            p += (size_t)NROWS * DTRANK * 2;           // 0.25MB

    // Weight conversions (transposed bf16)
    transpose_bf16_kernel<<<dim3(128, 32), 256, 0, stream>>>(W_in,  WinT,  DMODEL, 2*DINNER, 2*DINNER);
    transpose_bf16_kernel<<<dim3(4, 64),   256, 0, stream>>>(W_x,   WxT,   DINNER, 96, XROW);
    transpose_bf16_kernel<<<dim3(64, 2),   256, 0, stream>>>(W_dt,  WdtT,  DTRANK, DINNER, DINNER);
    transpose_bf16_kernel<<<dim3(32, 64),  256, 0, stream>>>(W_out, WoutT, DINNER, DMODEL, DMODEL);

    // 1. RMSNorm -> h bf16
    rmsnorm_kernel<<<NROWS, 256, 0, stream>>>(x0, norm_w, h_bf);

    // 2. xz = h @ W_in   [2048,1024]x[1024,4096] -> bf16
    gemm_bf16_kernel<0, true, 128, 64><<<dim3(32, 16, 1), 256, 0, stream>>>(
        h_bf, DMODEL, WinT, DMODEL, xz_bf, 2*DINNER, DMODEL, nullptr, nullptr, 0);

    // 3. causal conv + silu -> xc bf16
    conv_silu_kernel<<<(NROWS * DINNER) / 256, 256, 0, stream>>>(xz_bf, conv_w, conv_b, xc_bf);

    // 4. x_proj split-K=8 partials -> Pw slices
    gemm_bf16_kernel<4, false, 128, 64><<<dim3(1, 16, 8), 256, 0, stream>>>(
        xc_bf, DINNER, WxT, DINNER, Pw, XROW, DINNER / 8, nullptr, nullptr, NROWS * XROW);

    // 4b. reduce partials -> dt_bf + BC
    xproj_reduce_kernel<<<(NROWS * XROW) / 256, 256, 0, stream>>>(Pw, dt_bf, BC);

    // 5. delta = softplus(dt @ W_dt + b_dt)  [2048,64]x[64,2048] -> fp32 (1 K-iter)
    gemm_bf16_kernel<1, false, 128, 64><<<dim3(16, 16, 1), 256, 0, stream>>>(
        dt_bf, DTRANK, WdtT, DTRANK, delta, DINNER, DTRANK, b_dt, nullptr, 0);

    // 6. chunked selective scan (+ fused ymod) -> y_bf
    dim3 sgrid(NC, DINNER / 256, BATCH);
    scan_chunk_kernel<false><<<sgrid, 256, 0, stream>>>(
        delta, xc_bf, BC, A, Pbuf, Sbuf, nullptr, nullptr, nullptr);
    scan_combine_kernel<<<(BATCH * DINNER * DSTATE) / 256, 256, 0, stream>>>(Pbuf, Sbuf);
    scan_chunk_kernel<true><<<sgrid, 256, 0, stream>>>(
        delta, xc_bf, BC, A, Pbuf, Sbuf, xz_bf, Dp, y_bf);

    // 7. out = x0 + y @ W_out  [2048,2048]x[2048,1024] -> fp32 (TN=64, 256 blocks)
    gemm_bf16_kernel<2, false, 64, 64><<<dim3(16, 16, 1), 256, 0, stream>>>(
        y_bf, DINNER, WoutT, DINNER, out, DMODEL, DINNER, nullptr, x0, DMODEL);
}

// Round 5
// 259.712 us; speedup vs baseline: 5.1487x; 1.0722x over previous
//
#include <hip/hip_runtime.h>
#include <hip/hip_bf16.h>
#include <math.h>

// Problem constants
#define BATCH 2
#define LSEQ 1024
#define DMODEL 1024
#define DINNER 2048
#define DSTATE 16
#define DTRANK 64
#define NROWS (BATCH * LSEQ)   // 2048 token rows
#define XROW 128               // padded x_proj width (96 -> 128)
#define NC 32                  // scan chunks
#define TCH (LSEQ / NC)        // 32 timesteps per chunk

typedef __bf16 bf16;
typedef __attribute__((ext_vector_type(8))) __bf16 bf16x8;
typedef __attribute__((ext_vector_type(2))) __bf16 bf16x2;
typedef __attribute__((ext_vector_type(4))) float floatx4;

// ---------------------------------------------------------------------------
// bf16 MFMA GEMM. TM=128, templated TN/BK. global_load_lds width-16 staging
// with XOR-swizzled K-chunks (8-way LDS conflict -> free 2-way).
// MODE 0: C = acc                MODE 1: C = softplus(acc + bias[n])
// MODE 2: C = acc + resid[gm*ldr+gn]
// MODE 4: C[z*ldr + gm*ldc+gn] = acc   (split-K partials)
// ---------------------------------------------------------------------------
template<int MODE, bool BF16OUT, int TN_, int BK_>
__global__ __launch_bounds__(256) void gemm_bf16_kernel(
    const bf16* __restrict__ A, int lda,
    const bf16* __restrict__ Bt, int ldb,
    void* __restrict__ Cv, int ldc,
    int Ksplit,
    const float* __restrict__ bias,
    const float* __restrict__ resid, int ldr)
{
    constexpr int TMc  = 128;
    constexpr int CA   = BK_ / 8;                  // chunks per row
    constexpr int ISSA = TMc * BK_ * 2 / 4096;     // 4-KB issues for A
    constexpr int ISSB = TN_ * BK_ * 2 / 4096;
    constexpr int NB   = TN_ / 32;                 // B frags per wave
    constexpr int NH   = BK_ / 32;                 // K halves per iter

    __shared__ __attribute__((aligned(16))) bf16 As[TMc * BK_];
    __shared__ __attribute__((aligned(16))) bf16 Bs[TN_ * BK_];

    const int tid  = threadIdx.x;
    const int lane = tid & 63;
    const int wave = tid >> 6;
    const int l15  = lane & 15;
    const int quad = lane >> 4;
    const int wm   = (wave >> 1) * 64;
    const int wn   = (wave & 1) * (TN_ / 2);

    const int row0 = blockIdx.y * TMc;
    const int col0 = blockIdx.x * TN_;
    const long kbase = (long)blockIdx.z * Ksplit;

    const bf16* gA[ISSA]; bf16* lA[ISSA];
    const bf16* gB[ISSB]; bf16* lB[ISSB];
    #pragma unroll
    for (int i = 0; i < ISSA; ++i) {
        int c = i * 256 + wave * 64 + lane;
        int r = c / CA;
        int kc = (c % CA) ^ (r % CA);
        gA[i] = A + (size_t)(row0 + r) * lda + kbase + kc * 8;
        lA[i] = As + (size_t)(i * 256 + wave * 64) * 8;
    }
    #pragma unroll
    for (int i = 0; i < ISSB; ++i) {
        int c = i * 256 + wave * 64 + lane;
        int r = c / CA;
        int kc = (c % CA) ^ (r % CA);
        gB[i] = Bt + (size_t)(col0 + r) * ldb + kbase + kc * 8;
        lB[i] = Bs + (size_t)(i * 256 + wave * 64) * 8;
    }

    floatx4 acc[4][NB];
    #pragma unroll
    for (int i = 0; i < 4; ++i)
        #pragma unroll
        for (int j = 0; j < NB; ++j)
            acc[i][j] = (floatx4){0.f, 0.f, 0.f, 0.f};

    const int kiters = Ksplit / BK_;
    for (int kk = 0; kk < kiters; ++kk) {
        __syncthreads();
        #pragma unroll
        for (int i = 0; i < ISSA; ++i) {
            __builtin_amdgcn_global_load_lds(
                (const __attribute__((address_space(1))) void*)gA[i],
                (__attribute__((address_space(3))) void*)lA[i], 16, 0, 0);
            gA[i] += BK_;
        }
        #pragma unroll
        for (int i = 0; i < ISSB; ++i) {
            __builtin_amdgcn_global_load_lds(
                (const __attribute__((address_space(1))) void*)gB[i],
                (__attribute__((address_space(3))) void*)lB[i], 16, 0, 0);
            gB[i] += BK_;
        }
        __syncthreads();

        #pragma unroll
        for (int h = 0; h < NH; ++h) {
            bf16x8 af[4], bfr[NB];
            #pragma unroll
            for (int i = 0; i < 4; ++i) {
                int r = wm + i * 16 + l15;
                af[i] = *(const bf16x8*)&As[(size_t)r * BK_ +
                          (((h * 4 + quad) ^ (r % CA)) * 8)];
            }
            #pragma unroll
            for (int j = 0; j < NB; ++j) {
                int r = wn + j * 16 + l15;
                bfr[j] = *(const bf16x8*)&Bs[(size_t)r * BK_ +
                           (((h * 4 + quad) ^ (r % CA)) * 8)];
            }
            #pragma unroll
            for (int i = 0; i < 4; ++i)
                #pragma unroll
                for (int j = 0; j < NB; ++j)
                    acc[i][j] = __builtin_amdgcn_mfma_f32_16x16x32_bf16(
                                    af[i], bfr[j], acc[i][j], 0, 0, 0);
        }
    }

    #pragma unroll
    for (int i = 0; i < 4; ++i) {
        #pragma unroll
        for (int j = 0; j < NB; ++j) {
            const int gn = col0 + wn + j * 16 + l15;
            #pragma unroll
            for (int r = 0; r < 4; ++r) {
                const int gm = row0 + wm + i * 16 + quad * 4 + r;
                float v = acc[i][j][r];
                if (MODE == 1) {
                    v += bias[gn];
                    v = (v > 20.0f) ? v : log1pf(__expf(v));
                }
                if (MODE == 2) v += resid[(size_t)gm * ldr + gn];
                if (MODE == 4) {
                    ((float*)Cv)[(size_t)blockIdx.z * ldr + (size_t)gm * ldc + gn] = v;
                } else if (BF16OUT) {
                    ((bf16*)Cv)[(size_t)gm * ldc + gn] = (bf16)v;
                } else {
                    ((float*)Cv)[(size_t)gm * ldc + gn] = v;
                }
            }
        }
    }
}

// ---------------------------------------------------------------------------
// Fused prep: 4 weight transposes (fp32 -> bf16, transposed, zero-pad) and
// RMSNorm, dispatched by block range.
//   [0,4096)      W_in  1024x4096 -> WinT
//   [4096,4352)   W_x   2048x96   -> WxT (Npad 128)
//   [4352,4480)   W_dt  64x2048   -> WdtT
//   [4480,6528)   W_out 2048x1024 -> WoutT
//   [6528,8576)   rmsnorm rows
// ---------------------------------------------------------------------------
__global__ __launch_bounds__(256) void prep_kernel(
    const float* __restrict__ W_in,  bf16* __restrict__ WinT,
    const float* __restrict__ W_x,   bf16* __restrict__ WxT,
    const float* __restrict__ W_dt,  bf16* __restrict__ WdtT,
    const float* __restrict__ W_out, bf16* __restrict__ WoutT,
    const float* __restrict__ x0, const float* __restrict__ norm_w,
    bf16* __restrict__ h)
{
    __shared__ float smem[32 * 33];
    const int bid = blockIdx.x;
    const int tid = threadIdx.x;

    if (bid < 6528) {
        const float* W; bf16* Wt; int K, N, Npad, bx, by;
        if (bid < 4096)      { W = W_in;  Wt = WinT;  K = 1024; N = 4096; Npad = 4096; bx = bid & 127, by = bid >> 7; }
        else if (bid < 4352) { int l = bid - 4096; W = W_x;  Wt = WxT;  K = 2048; N = 96;   Npad = 128;  bx = l & 3,  by = l >> 2; }
        else if (bid < 4480) { int l = bid - 4352; W = W_dt; Wt = WdtT; K = 64;   N = 2048; Npad = 2048; bx = l & 63, by = l >> 6; }
        else                 { int l = bid - 4480; W = W_out;Wt = WoutT;K = 2048; N = 1024; Npad = 1024; bx = l & 31, by = l >> 5; }
        float (*tile)[33] = (float(*)[33])smem;
        const int n0 = bx * 32, k0 = by * 32;
        const int tx = tid & 31, ty = tid >> 5;
        #pragma unroll
        for (int i = 0; i < 32; i += 8) {
            int k = k0 + ty + i, n = n0 + tx;
            tile[ty + i][tx] = (k < K && n < N) ? W[(size_t)k * N + n] : 0.0f;
        }
        __syncthreads();
        #pragma unroll
        for (int i = 0; i < 32; i += 8) {
            int n = n0 + ty + i, k = k0 + tx;
            if (n < Npad && k < K)
                Wt[(size_t)n * K + k] = (bf16)tile[tx][ty + i];
        }
    } else {
        const int row = bid - 6528;
        const float* xr = x0 + (size_t)row * DMODEL;
        float4 v = *(const float4*)(xr + tid * 4);
        float ss = v.x * v.x + v.y * v.y + v.z * v.z + v.w * v.w;
        #pragma unroll
        for (int m = 32; m >= 1; m >>= 1) ss += __shfl_xor(ss, m);
        if ((tid & 63) == 0) smem[tid >> 6] = ss;
        __syncthreads();
        float total = smem[0] + smem[1] + smem[2] + smem[3];
        float scale = rsqrtf(total * (1.0f / DMODEL) + 1e-5f);
        float4 wv = *(const float4*)(norm_w + tid * 4);
        union { bf16 b[4]; uint2 u; } pk;
        pk.b[0] = (bf16)(v.x * scale * wv.x);
        pk.b[1] = (bf16)(v.y * scale * wv.y);
        pk.b[2] = (bf16)(v.z * scale * wv.z);
        pk.b[3] = (bf16)(v.w * scale * wv.w);
        *(uint2*)(h + (size_t)row * DMODEL + tid * 4) = pk.u;
    }
}

// ---------------------------------------------------------------------------
// Causal depthwise conv (K=4) + bias + SiLU, 2 channels/thread.
// ---------------------------------------------------------------------------
__global__ __launch_bounds__(256) void conv_silu_kernel(
    const bf16* __restrict__ xz, const float* __restrict__ conv_w,
    const float* __restrict__ conv_b, bf16* __restrict__ xc)
{
    int idx = blockIdx.x * 256 + threadIdx.x;     // over NROWS*DINNER/2
    int c2 = (idx & (DINNER / 2 - 1)) * 2;
    int row = idx >> 10;
    int l = row & (LSEQ - 1);
    float4 wA = *(const float4*)&conv_w[c2 * 4];
    float4 wB = *(const float4*)&conv_w[c2 * 4 + 4];
    float2 bb = *(const float2*)&conv_b[c2];
    const bf16* xr = xz + (size_t)row * (2 * DINNER) + c2;
    bf16x2 p0 = *(const bf16x2*)xr;
    float a0 = bb.x + (float)p0[0] * wA.w;
    float a1 = bb.y + (float)p0[1] * wB.w;
    if (l >= 1) { bf16x2 p = *(const bf16x2*)(xr - 2 * DINNER); a0 += (float)p[0] * wA.z; a1 += (float)p[1] * wB.z; }
    if (l >= 2) { bf16x2 p = *(const bf16x2*)(xr - 4 * DINNER); a0 += (float)p[0] * wA.y; a1 += (float)p[1] * wB.y; }
    if (l >= 3) { bf16x2 p = *(const bf16x2*)(xr - 6 * DINNER); a0 += (float)p[0] * wA.x; a1 += (float)p[1] * wB.x; }
    a0 = a0 / (1.0f + __expf(-a0));
    a1 = a1 / (1.0f + __expf(-a1));
    bf16x2 o; o[0] = (bf16)a0; o[1] = (bf16)a1;
    *(bf16x2*)(xc + (size_t)row * DINNER + c2) = o;
}

// ---------------------------------------------------------------------------
// Reduce x_proj split-K partials: sum 8 slices of [NROWS][128].
// cols 0..63 -> dt_bf (bf16), cols 64..95 -> BC fp32 [NROWS][32].
// ---------------------------------------------------------------------------
__global__ __launch_bounds__(256) void xproj_reduce_kernel(
    const float* __restrict__ Pw, bf16* __restrict__ dt,
    float* __restrict__ BC)
{
    int idx = blockIdx.x * 256 + threadIdx.x;   // NROWS*128
    int row = idx >> 7, c = idx & 127;
    float s = 0.0f;
    #pragma unroll
    for (int k = 0; k < 8; ++k)
        s += Pw[(size_t)k * NROWS * XROW + idx];
    if (c < 64) dt[(size_t)row * 64 + c] = (bf16)s;
    else if (c < 96) BC[(size_t)row * 32 + (c - 64)] = s;
}

// ---------------------------------------------------------------------------
// Chunked selective scan. Lane = (b, chunk, d); 16 states in registers.
// P/S layout [b][k][n][DINNER] for fully-coalesced scalar access.
// Phase 1: P = prod(dA), S = local final state. Combine: chunk-serial fixup.
// Phase 2: re-run from true init, fused ymod epilogue -> ybf.
// ---------------------------------------------------------------------------
template<bool FINAL>
__global__ __launch_bounds__(256) void scan_chunk_kernel(
    const bf16* __restrict__ delta,   // [NROWS][DINNER] bf16
    const bf16* __restrict__ xc,      // [NROWS][DINNER]
    const float* __restrict__ BC,     // [NROWS][32]: B then C
    const float* __restrict__ A,      // [DINNER][DSTATE]
    float* __restrict__ Pbuf,         // [B][NC][16][DINNER]
    float* __restrict__ Sbuf,         // [B][NC][16][DINNER]
    const bf16* __restrict__ xz,      // res at col DINNER+d, stride 2*DINNER
    const float* __restrict__ Dp,     // [DINNER]
    bf16* __restrict__ ybf)           // [NROWS][DINNER]
{
    __shared__ float sBC[TCH][32];
    const int tid   = threadIdx.x;
    const int chunk = blockIdx.x;
    const int d     = blockIdx.y * 256 + tid;
    const int b     = blockIdx.z;
    const int row0  = b * LSEQ + chunk * TCH;

    {
        int t = tid >> 3, c4 = (tid & 7) * 4;
        *(float4*)&sBC[t][c4] = *(const float4*)&BC[(size_t)(row0 + t) * 32 + c4];
    }

    float Ad[16];
    #pragma unroll
    for (int j = 0; j < 4; ++j) {
        float4 av = *(const float4*)&A[(size_t)d * DSTATE + j * 4];
        Ad[j*4+0] = av.x; Ad[j*4+1] = av.y; Ad[j*4+2] = av.z; Ad[j*4+3] = av.w;
    }

    const size_t psbase = ((size_t)(b * NC + chunk) * DSTATE) * DINNER + d;
    float S[16], P[16];
    if (FINAL) {
        #pragma unroll
        for (int n = 0; n < 16; ++n) S[n] = Sbuf[psbase + (size_t)n * DINNER];
    } else {
        #pragma unroll
        for (int n = 0; n < 16; ++n) { S[n] = 0.0f; P[n] = 1.0f; }
    }
    float Dpd = FINAL ? Dp[d] : 0.0f;

    __syncthreads();

    #pragma unroll 2
    for (int t = 0; t < TCH; ++t) {
        const size_t row = (size_t)(row0 + t);
        float dv = (float)delta[row * DINNER + d];
        float xv = (float)xc[row * DINNER + d];
        float u  = dv * xv;
        float yp[4] = {0.f, 0.f, 0.f, 0.f};
        #pragma unroll
        for (int n = 0; n < 16; ++n) {
            float dA = __expf(dv * Ad[n]);
            S[n] = dA * S[n] + u * sBC[t][n];
            if (FINAL) {
                yp[n & 3] += S[n] * sBC[t][16 + n];
            } else {
                P[n] *= dA;
            }
        }
        if (FINAL) {
            float y = (yp[0] + yp[1]) + (yp[2] + yp[3]);
            float res = (float)xz[row * (2 * DINNER) + DINNER + d];
            float sres = res / (1.0f + __expf(-res));
            ybf[row * DINNER + d] = (bf16)((y + xv * Dpd) * sres);
        }
    }

    if (!FINAL) {
        #pragma unroll
        for (int n = 0; n < 16; ++n) {
            Pbuf[psbase + (size_t)n * DINNER] = P[n];
            Sbuf[psbase + (size_t)n * DINNER] = S[n];
        }
    }
}

// Per-(b,n,d) serial combine over chunks: Sbuf[k] <- true initial state.
__global__ __launch_bounds__(256) void scan_combine_kernel(
    const float* __restrict__ Pbuf, float* __restrict__ Sbuf)
{
    int gid = blockIdx.x * 256 + threadIdx.x;   // B * 16 * DINNER = 65536
    int b = gid >> 15;
    int nd = gid & 32767;
    float carry = 0.0f;
    for (int k = 0; k < NC; ++k) {
        size_t off = ((size_t)(b * NC + k) << 15) + nd;
        float pk = Pbuf[off];
        float sk = Sbuf[off];
        Sbuf[off] = carry;
        carry = pk * carry + sk;
    }
}

// ---------------------------------------------------------------------------
extern "C" void kernel_launch(void* const* d_in, const int* in_sizes, int n_in,
                              void* d_out, int out_size, void* d_ws, size_t ws_size,
                              hipStream_t stream)
{
    const float* x0     = (const float*)d_in[0];
    const float* norm_w = (const float*)d_in[1];
    const float* W_in   = (const float*)d_in[2];   // [1024,4096]
    const float* conv_w = (const float*)d_in[3];
    const float* conv_b = (const float*)d_in[4];
    const float* W_x    = (const float*)d_in[5];   // [2048,96]
    const float* W_dt   = (const float*)d_in[6];   // [64,2048]
    const float* b_dt   = (const float*)d_in[7];
    const float* A      = (const float*)d_in[8];
    const float* Dp     = (const float*)d_in[9];
    const float* W_out  = (const float*)d_in[10];  // [2048,1024]
    float* out = (float*)d_out;

    // Workspace layout (~75 MB)
    char* p = (char*)d_ws;
    bf16*  xz_bf = (bf16*)p;            p += (size_t)NROWS * 2 * DINNER * 2;       // 16MB
    float* Pw    = (float*)p;           p += (size_t)8 * NROWS * XROW * 4;         // 8MB
    float* BC    = (float*)p;           p += (size_t)NROWS * 32 * 4;               // 0.25MB
    bf16*  delta = (bf16*)p;            p += (size_t)NROWS * DINNER * 2;           // 8MB
    float* Pbuf  = (float*)p;           p += (size_t)BATCH * NC * DINNER * 16 * 4; // 8MB
    float* Sbuf  = (float*)p;           p += (size_t)BATCH * NC * DINNER * 16 * 4; // 8MB
    bf16*  h_bf  = (bf16*)p;            p += (size_t)NROWS * DMODEL * 2;           // 4MB
    bf16*  xc_bf = (bf16*)p;            p += (size_t)NROWS * DINNER * 2;           // 8MB
    bf16*  y_bf  = (bf16*)p;            p += (size_t)NROWS * DINNER * 2;           // 8MB
    bf16*  WinT  = (bf16*)p;            p += (size_t)(2*DINNER) * DMODEL * 2;      // 8MB
    bf16*  WxT   = (bf16*)p;            p += (size_t)XROW * DINNER * 2;            // 0.5MB
    bf16*  WdtT  = (bf16*)p;            p += (size_t)DINNER * DTRANK * 2;          // 0.25MB
    bf16*  WoutT = (bf16*)p;            p += (size_t)DMODEL * DINNER * 2;          // 4MB
    bf16*  dt_bf = (bf16*)p;            p += (size_t)NROWS * DTRANK * 2;           // 0.25MB

    // 1. Fused prep: weight transposes + RMSNorm
    prep_kernel<<<8576, 256, 0, stream>>>(W_in, WinT, W_x, WxT, W_dt, WdtT,
                                          W_out, WoutT, x0, norm_w, h_bf);

    // 2. xz = h @ W_in   [2048,1024]x[1024,4096] -> bf16
    gemm_bf16_kernel<0, true, 128, 64><<<dim3(32, 16, 1), 256, 0, stream>>>(
        h_bf, DMODEL, WinT, DMODEL, xz_bf, 2*DINNER, DMODEL, nullptr, nullptr, 0);

    // 3. causal conv + silu -> xc bf16 (2 ch/thread)
    conv_silu_kernel<<<(NROWS * DINNER / 2) / 256, 256, 0, stream>>>(xz_bf, conv_w, conv_b, xc_bf);

    // 4. x_proj split-K=8 partials -> Pw slices
    gemm_bf16_kernel<4, false, 128, 64><<<dim3(1, 16, 8), 256, 0, stream>>>(
        xc_bf, DINNER, WxT, DINNER, Pw, XROW, DINNER / 8, nullptr, nullptr, NROWS * XROW);

    // 4b. reduce partials -> dt_bf + BC
    xproj_reduce_kernel<<<(NROWS * XROW) / 256, 256, 0, stream>>>(Pw, dt_bf, BC);

    // 5. delta = softplus(dt @ W_dt + b_dt)  -> bf16 (1 K-iter)
    gemm_bf16_kernel<1, true, 128, 64><<<dim3(16, 16, 1), 256, 0, stream>>>(
        dt_bf, DTRANK, WdtT, DTRANK, delta, DINNER, DTRANK, b_dt, nullptr, 0);

    // 6. chunked selective scan (+ fused ymod) -> y_bf
    dim3 sgrid(NC, DINNER / 256, BATCH);
    scan_chunk_kernel<false><<<sgrid, 256, 0, stream>>>(
        delta, xc_bf, BC, A, Pbuf, Sbuf, nullptr, nullptr, nullptr);
    scan_combine_kernel<<<(BATCH * DINNER * DSTATE) / 256, 256, 0, stream>>>(Pbuf, Sbuf);
    scan_chunk_kernel<true><<<sgrid, 256, 0, stream>>>(
        delta, xc_bf, BC, A, Pbuf, Sbuf, xz_bf, Dp, y_bf);

    // 7. out = x0 + y @ W_out  [2048,2048]x[2048,1024] -> fp32 (TN=64, 256 blocks)
    gemm_bf16_kernel<2, false, 64, 64><<<dim3(16, 16, 1), 256, 0, stream>>>(
        y_bf, DINNER, WoutT, DINNER, out, DMODEL, DINNER, nullptr, x0, DMODEL);
}